// Round 3
// baseline (227.590 us; speedup 1.0000x reference)
//
#include <hip/hip_runtime.h>

#define H 1024
#define B_ 4
#define T_ 512
#define NCTX 2048
#define NH 16
#define HD 64

typedef __attribute__((ext_vector_type(8))) short bf16x8;
typedef __attribute__((ext_vector_type(4))) float f32x4;
typedef __attribute__((ext_vector_type(4))) short s16x4;

__device__ __forceinline__ ushort f2b(float f) {
  union { float f; unsigned u; } v; v.f = f;
  unsigned u = v.u;
  unsigned r = (u + 0x7FFFu + ((u >> 16) & 1u)) >> 16;
  return (ushort)r;
}

// ---------------- prep kernels ----------------

__global__ void cvt_kernel(const float* __restrict__ src, ushort* __restrict__ dst) {
  int i = blockIdx.x * blockDim.x + threadIdx.x;  // float4 index, n4 = 262144 per 1M matrix
  float4 v = ((const float4*)src)[i];
  s16x4 o;
  o[0] = (short)f2b(v.x); o[1] = (short)f2b(v.y);
  o[2] = (short)f2b(v.z); o[3] = (short)f2b(v.w);
  ((s16x4*)dst)[i] = o;
}

__global__ void prep_q_kernel(const float* __restrict__ q, const float* __restrict__ iemb,
                              const int* __restrict__ curp, ushort* __restrict__ out) {
  int cur = curp[0];
  int i = blockIdx.x * blockDim.x + threadIdx.x;  // float4 index, total 524288
  int c4 = i & 255;                               // column (in float4 units), row len = 256
  float4 v = ((const float4*)q)[i];
  float4 e = ((const float4*)(iemb + (size_t)cur * H))[c4];
  s16x4 o;
  o[0] = (short)f2b(v.x + e.x); o[1] = (short)f2b(v.y + e.y);
  o[2] = (short)f2b(v.z + e.z); o[3] = (short)f2b(v.w + e.w);
  ((s16x4*)out)[i] = o;
}

__global__ void prep_ctx_kernel(const float* __restrict__ ctx, const float* __restrict__ iemb,
                                const float* __restrict__ bemb, const int* __restrict__ ids,
                                const int* __restrict__ bars, ushort* __restrict__ out) {
  int i = blockIdx.x * blockDim.x + threadIdx.x;  // float4 index, total 2097152
  int row = i >> 8;                               // b*NCTX + n
  int c4 = i & 255;
  int id = ids[row];
  int bar = bars[row];
  bar = bar < 0 ? 0 : (bar > 7 ? 7 : bar);
  float4 v = ((const float4*)ctx)[i];
  float4 e = ((const float4*)(iemb + (size_t)id * H))[c4];
  float4 g = ((const float4*)(bemb + (size_t)bar * H))[c4];
  s16x4 o;
  o[0] = (short)f2b(v.x + e.x + g.x); o[1] = (short)f2b(v.y + e.y + g.y);
  o[2] = (short)f2b(v.z + e.z + g.z); o[3] = (short)f2b(v.w + e.w + g.w);
  ((s16x4*)out)[i] = o;
}

// ---------------- GEMM: C[M][1024] = A[M][1024](bf16) @ W[1024][1024]^T(bf16) + bias ----------------
// MODE 0: bf16 row-major out; MODE 1: bf16 transposed (VT[b][c][n], M = b*2048+n);
// MODE 2: f32 row-major out.

template <int MODE>
__global__ __launch_bounds__(256) void gemm_k(const ushort* __restrict__ A,
                                              const ushort* __restrict__ W,
                                              const float* __restrict__ bias,
                                              void* __restrict__ Cout) {
  __shared__ ushort As[128][40];  // +8 pad: 80B row stride -> conflict-free-ish
  __shared__ ushort Bs[128][40];
  const int tid = threadIdx.x;
  const int lane = tid & 63;
  const int wv = tid >> 6;
  const int wr = wv >> 1, wc = wv & 1;
  const int lo = lane & 15, hi = lane >> 4;
  const int row0 = blockIdx.y * 128, col0 = blockIdx.x * 128;

  f32x4 acc[4][4];
#pragma unroll
  for (int m = 0; m < 4; m++)
#pragma unroll
    for (int n = 0; n < 4; n++) acc[m][n] = (f32x4){0.f, 0.f, 0.f, 0.f};

  for (int kt = 0; kt < H; kt += 32) {
#pragma unroll
    for (int i = 0; i < 2; i++) {
      int seg = tid + i * 256;       // 0..511
      int r = seg >> 2, s = seg & 3; // 128 rows x 4 x 16B
      *(bf16x8*)(&As[r][s * 8]) = *(const bf16x8*)(A + (size_t)(row0 + r) * H + kt + s * 8);
      *(bf16x8*)(&Bs[r][s * 8]) = *(const bf16x8*)(W + (size_t)(col0 + r) * H + kt + s * 8);
    }
    __syncthreads();
    bf16x8 af[4], bfr[4];
#pragma unroll
    for (int m = 0; m < 4; m++) af[m] = *(const bf16x8*)(&As[wr * 64 + m * 16 + lo][hi * 8]);
#pragma unroll
    for (int n = 0; n < 4; n++) bfr[n] = *(const bf16x8*)(&Bs[wc * 64 + n * 16 + lo][hi * 8]);
#pragma unroll
    for (int m = 0; m < 4; m++)
#pragma unroll
      for (int n = 0; n < 4; n++)
        acc[m][n] = __builtin_amdgcn_mfma_f32_16x16x32_bf16(af[m], bfr[n], acc[m][n], 0, 0, 0);
    __syncthreads();
  }

#pragma unroll
  for (int m = 0; m < 4; m++) {
    int gr0 = row0 + wr * 64 + m * 16 + hi * 4;  // +reg for rows
#pragma unroll
    for (int n = 0; n < 4; n++) {
      int gc = col0 + wc * 64 + n * 16 + lo;
      float bv = bias[gc];
      if (MODE == 0) {
        ushort* C = (ushort*)Cout;
#pragma unroll
        for (int r = 0; r < 4; r++)
          C[(size_t)(gr0 + r) * H + gc] = f2b(acc[m][n][r] + bv);
      } else if (MODE == 1) {
        ushort* C = (ushort*)Cout;
        int bb = gr0 >> 11, n0 = gr0 & 2047;
        s16x4 o;
#pragma unroll
        for (int r = 0; r < 4; r++) o[r] = (short)f2b(acc[m][n][r] + bv);
        *(s16x4*)(C + (size_t)bb * (H * NCTX) + (size_t)gc * NCTX + n0) = o;
      } else {
        float* C = (float*)Cout;
#pragma unroll
        for (int r = 0; r < 4; r++)
          C[(size_t)(gr0 + r) * H + gc] = acc[m][n][r] + bv;
      }
    }
  }
}

// ---------------- flash attention ----------------
// grid: 512 blocks = b*128 + h*8 + qt ; 4 waves, wave w owns q rows [qt*64+w*16, +16)

__global__ __launch_bounds__(256) void attn_k(const ushort* __restrict__ Q,
                                              const ushort* __restrict__ K,
                                              const ushort* __restrict__ VT,
                                              const int* __restrict__ ids,
                                              const int* __restrict__ curp,
                                              ushort* __restrict__ O) {
  __shared__ ushort Ks[64][72];      // [kv][d], +8 pad
  __shared__ ushort Vs[64][72];      // [d][kv], +8 pad
  __shared__ ushort Ps[4][16][72];   // per-wave P tile [q][kv]
  const int blk = blockIdx.x;
  const int qt = blk & 7;
  const int h = (blk >> 3) & 15;
  const int b = blk >> 7;
  const int cur = curp[0];
  const int tid = threadIdx.x, lane = tid & 63, w = tid >> 6;
  const int lo = lane & 15, hi = lane >> 4;

  const ushort* Qp = Q + ((size_t)(b * T_ + qt * 64 + w * 16 + lo)) * H + h * HD;
  bf16x8 qf0 = *(const bf16x8*)(Qp + hi * 8);
  bf16x8 qf1 = *(const bf16x8*)(Qp + 32 + hi * 8);

  f32x4 oacc[4];
#pragma unroll
  for (int d = 0; d < 4; d++) oacc[d] = (f32x4){0.f, 0.f, 0.f, 0.f};
  float mrow[4], lrow[4];
#pragma unroll
  for (int r = 0; r < 4; r++) { mrow[r] = -1e30f; lrow[r] = 0.f; }

  const int* idb = ids + b * NCTX;

  for (int kv0 = 0; kv0 < NCTX; kv0 += 64) {
    // stage full 64x64 bf16 tiles: 512 segments x 16B, 2 per thread
#pragma unroll
    for (int i = 0; i < 2; i++) {
      int seg = tid + i * 256;        // 0..511
      int r = seg >> 3, s = seg & 7;  // 64 rows x 8 x 16B
      *(bf16x8*)(&Ks[r][s * 8]) =
          *(const bf16x8*)(K + ((size_t)(b * NCTX + kv0 + r)) * H + h * HD + s * 8);
      *(bf16x8*)(&Vs[r][s * 8]) =
          *(const bf16x8*)(VT + (size_t)b * (H * NCTX) + (size_t)(h * HD + r) * NCTX + kv0 + s * 8);
    }
    __syncthreads();

    // scores: S = Q K^T, per wave 16x64
    f32x4 sc[4];
#pragma unroll
    for (int nt = 0; nt < 4; nt++) {
      bf16x8 kf0 = *(const bf16x8*)(&Ks[nt * 16 + lo][hi * 8]);
      bf16x8 kf1 = *(const bf16x8*)(&Ks[nt * 16 + lo][32 + hi * 8]);
      f32x4 z = (f32x4){0.f, 0.f, 0.f, 0.f};
      z = __builtin_amdgcn_mfma_f32_16x16x32_bf16(qf0, kf0, z, 0, 0, 0);
      sc[nt] = __builtin_amdgcn_mfma_f32_16x16x32_bf16(qf1, kf1, z, 0, 0, 0);
    }

    // mask + scale
    float sv[4][4];  // [nt][reg]
#pragma unroll
    for (int nt = 0; nt < 4; nt++) {
      int kvc = kv0 + nt * 16 + lo;
      bool keep = (idb[kvc] != cur);
#pragma unroll
      for (int r = 0; r < 4; r++) {
        float x = sc[nt][r] * 0.125f;
        sv[nt][r] = keep ? x : -1e30f;
      }
    }

    // online softmax per row (row = hi*4 + r)
#pragma unroll
    for (int r = 0; r < 4; r++) {
      float x = fmaxf(fmaxf(sv[0][r], sv[1][r]), fmaxf(sv[2][r], sv[3][r]));
      x = fmaxf(x, __shfl_xor(x, 1, 16));
      x = fmaxf(x, __shfl_xor(x, 2, 16));
      x = fmaxf(x, __shfl_xor(x, 4, 16));
      x = fmaxf(x, __shfl_xor(x, 8, 16));
      float mn = fmaxf(mrow[r], x);
      float scal = __expf(mrow[r] - mn);
      mrow[r] = mn;
      float rs = 0.f;
#pragma unroll
      for (int nt = 0; nt < 4; nt++) {
        float p = __expf(sv[nt][r] - mn);
        sv[nt][r] = p;
        rs += p;
      }
      rs += __shfl_xor(rs, 1, 16);
      rs += __shfl_xor(rs, 2, 16);
      rs += __shfl_xor(rs, 4, 16);
      rs += __shfl_xor(rs, 8, 16);
      lrow[r] = lrow[r] * scal + rs;
#pragma unroll
      for (int d = 0; d < 4; d++) oacc[d][r] *= scal;
    }

    // P -> LDS (bf16), transposing to A-fragment layout
#pragma unroll
    for (int nt = 0; nt < 4; nt++)
#pragma unroll
      for (int r = 0; r < 4; r++)
        Ps[w][hi * 4 + r][nt * 16 + lo] = f2b(sv[nt][r]);
    __syncthreads();

    // PV: oacc += P @ V
#pragma unroll
    for (int ks = 0; ks < 2; ks++) {
      bf16x8 pa = *(const bf16x8*)(&Ps[w][lo][ks * 32 + hi * 8]);
#pragma unroll
      for (int d = 0; d < 4; d++) {
        bf16x8 vf = *(const bf16x8*)(&Vs[d * 16 + lo][ks * 32 + hi * 8]);
        oacc[d] = __builtin_amdgcn_mfma_f32_16x16x32_bf16(pa, vf, oacc[d], 0, 0, 0);
      }
    }
    __syncthreads();
  }

  // normalize + store bf16
#pragma unroll
  for (int d = 0; d < 4; d++) {
#pragma unroll
    for (int r = 0; r < 4; r++) {
      int t = qt * 64 + w * 16 + hi * 4 + r;
      O[((size_t)(b * T_ + t)) * H + h * HD + d * 16 + lo] = f2b(oacc[d][r] / lrow[r]);
    }
  }
}

// ---------------- launch ----------------

extern "C" void kernel_launch(void* const* d_in, const int* in_sizes, int n_in,
                              void* d_out, int out_size, void* d_ws, size_t ws_size,
                              hipStream_t stream) {
  const float* query = (const float*)d_in[0];
  const float* context = (const float*)d_in[1];
  const int* ids = (const int*)d_in[2];
  const int* curp = (const int*)d_in[3];
  const int* bars = (const int*)d_in[4];
  const float* Wq = (const float*)d_in[5];
  const float* bq = (const float*)d_in[6];
  const float* Wk = (const float*)d_in[7];
  const float* bk = (const float*)d_in[8];
  const float* Wv = (const float*)d_in[9];
  const float* bv = (const float*)d_in[10];
  const float* Wo = (const float*)d_in[11];
  const float* bo = (const float*)d_in[12];
  const float* iemb = (const float*)d_in[13];
  const float* bemb = (const float*)d_in[14];
  float* out = (float*)d_out;

  ushort* ws = (ushort*)d_ws;
  ushort* Wqb = ws;                      // 1M shorts each
  ushort* Wkb = Wqb + (1u << 20);
  ushort* Wvb = Wkb + (1u << 20);
  ushort* Wob = Wvb + (1u << 20);
  ushort* qin = Wob + (1u << 20);        // 2M
  ushort* ctxb = qin + (2u << 20);       // 8M
  ushort* Qb = ctxb + (8u << 20);        // 2M
  ushort* Kb = Qb + (2u << 20);          // 8M
  ushort* VTb = Kb + (8u << 20);         // 8M
  ushort* AOb = VTb + (8u << 20);        // 2M  -> total 34M shorts = 68MB

  cvt_kernel<<<1024, 256, 0, stream>>>(Wq, Wqb);
  cvt_kernel<<<1024, 256, 0, stream>>>(Wk, Wkb);
  cvt_kernel<<<1024, 256, 0, stream>>>(Wv, Wvb);
  cvt_kernel<<<1024, 256, 0, stream>>>(Wo, Wob);
  prep_q_kernel<<<2048, 256, 0, stream>>>(query, iemb, curp, qin);
  prep_ctx_kernel<<<8192, 256, 0, stream>>>(context, iemb, bemb, ids, bars, ctxb);

  gemm_k<0><<<dim3(8, 16), 256, 0, stream>>>(qin, Wqb, bq, Qb);    // Q
  gemm_k<0><<<dim3(8, 64), 256, 0, stream>>>(ctxb, Wkb, bk, Kb);   // K
  gemm_k<1><<<dim3(8, 64), 256, 0, stream>>>(ctxb, Wvb, bv, VTb);  // V (transposed store)

  attn_k<<<512, 256, 0, stream>>>(Qb, Kb, VTb, ids, curp, AOb);

  gemm_k<2><<<dim3(8, 16), 256, 0, stream>>>(AOb, Wob, bo, out);   // out proj
}

// Round 4
// 188.624 us; speedup vs baseline: 1.2066x; 1.2066x over previous
//
#include <hip/hip_runtime.h>

#define H 1024
#define B_ 4
#define T_ 512
#define NCTX 2048
#define NH 16
#define HD 64

typedef __attribute__((ext_vector_type(8))) short bf16x8;
typedef __attribute__((ext_vector_type(4))) float f32x4;
typedef __attribute__((ext_vector_type(4))) short s16x4;

__device__ __forceinline__ ushort f2b(float f) {
  union { float f; unsigned u; } v; v.f = f;
  unsigned u = v.u;
  unsigned r = (u + 0x7FFFu + ((u >> 16) & 1u)) >> 16;
  return (ushort)r;
}

__device__ __forceinline__ void gld16(const void* g, void* l) {
  __builtin_amdgcn_global_load_lds((const __attribute__((address_space(1))) unsigned int*)g,
                                   (__attribute__((address_space(3))) unsigned int*)l, 16, 0, 0);
}

// ---------------- prep kernels ----------------

__global__ void cvt_kernel(const float* __restrict__ src, ushort* __restrict__ dst) {
  int i = blockIdx.x * blockDim.x + threadIdx.x;
  float4 v = ((const float4*)src)[i];
  s16x4 o;
  o[0] = (short)f2b(v.x); o[1] = (short)f2b(v.y);
  o[2] = (short)f2b(v.z); o[3] = (short)f2b(v.w);
  ((s16x4*)dst)[i] = o;
}

__global__ void prep_q_kernel(const float* __restrict__ q, const float* __restrict__ iemb,
                              const int* __restrict__ curp, ushort* __restrict__ out) {
  int cur = curp[0];
  int i = blockIdx.x * blockDim.x + threadIdx.x;
  int c4 = i & 255;
  float4 v = ((const float4*)q)[i];
  float4 e = ((const float4*)(iemb + (size_t)cur * H))[c4];
  s16x4 o;
  o[0] = (short)f2b(v.x + e.x); o[1] = (short)f2b(v.y + e.y);
  o[2] = (short)f2b(v.z + e.z); o[3] = (short)f2b(v.w + e.w);
  ((s16x4*)out)[i] = o;
}

__global__ void prep_ctx_kernel(const float* __restrict__ ctx, const float* __restrict__ iemb,
                                const float* __restrict__ bemb, const int* __restrict__ ids,
                                const int* __restrict__ bars, ushort* __restrict__ out) {
  int i = blockIdx.x * blockDim.x + threadIdx.x;
  int row = i >> 8;
  int c4 = i & 255;
  int id = ids[row];
  int bar = bars[row];
  bar = bar < 0 ? 0 : (bar > 7 ? 7 : bar);
  float4 v = ((const float4*)ctx)[i];
  float4 e = ((const float4*)(iemb + (size_t)id * H))[c4];
  float4 g = ((const float4*)(bemb + (size_t)bar * H))[c4];
  s16x4 o;
  o[0] = (short)f2b(v.x + e.x + g.x); o[1] = (short)f2b(v.y + e.y + g.y);
  o[2] = (short)f2b(v.z + e.z + g.z); o[3] = (short)f2b(v.w + e.w + g.w);
  ((s16x4*)out)[i] = o;
}

// ---------------- GEMM with global_load_lds staging ----------------
// C[M][1024] = A[M][1024] @ W[1024][1024]^T + bias
// MODE 0: bf16 out; MODE 1: bf16 transposed (VT[b][c][n]); MODE 2: f32 out.

template <int MODE>
__global__ __launch_bounds__(256) void gemm_k(const ushort* __restrict__ A,
                                              const ushort* __restrict__ W,
                                              const float* __restrict__ bias,
                                              void* __restrict__ Cout) {
  __shared__ ushort As[128 * 32];  // linear (gload_lds requires contiguous dest)
  __shared__ ushort Bs[128 * 32];
  const int tid = threadIdx.x;
  const int lane = tid & 63;
  const int wv = tid >> 6;
  const int wr = wv >> 1, wc = wv & 1;
  const int lo = lane & 15, hi = lane >> 4;
  const int row0 = blockIdx.y * 128, col0 = blockIdx.x * 128;

  f32x4 acc[4][4];
#pragma unroll
  for (int m = 0; m < 4; m++)
#pragma unroll
    for (int n = 0; n < 4; n++) acc[m][n] = (f32x4){0.f, 0.f, 0.f, 0.f};

  for (int kt = 0; kt < H; kt += 32) {
#pragma unroll
    for (int c = 0; c < 2; c++) {
      int ia = wv * 128 + c * 64 + lane;  // chunk index 0..511, 16B each
      int r = ia >> 2, s = ia & 3;
      gld16(A + (size_t)(row0 + r) * H + kt + s * 8, (char*)As + (wv * 128 + c * 64) * 16);
      gld16(W + (size_t)(col0 + r) * H + kt + s * 8, (char*)Bs + (wv * 128 + c * 64) * 16);
    }
    __syncthreads();
    bf16x8 af[4], bfr[4];
#pragma unroll
    for (int m = 0; m < 4; m++) af[m] = *(const bf16x8*)(As + (wr * 64 + m * 16 + lo) * 32 + hi * 8);
#pragma unroll
    for (int n = 0; n < 4; n++) bfr[n] = *(const bf16x8*)(Bs + (wc * 64 + n * 16 + lo) * 32 + hi * 8);
#pragma unroll
    for (int m = 0; m < 4; m++)
#pragma unroll
      for (int n = 0; n < 4; n++)
        acc[m][n] = __builtin_amdgcn_mfma_f32_16x16x32_bf16(af[m], bfr[n], acc[m][n], 0, 0, 0);
    __syncthreads();
  }

#pragma unroll
  for (int m = 0; m < 4; m++) {
    int gr0 = row0 + wr * 64 + m * 16 + hi * 4;
#pragma unroll
    for (int n = 0; n < 4; n++) {
      int gc = col0 + wc * 64 + n * 16 + lo;
      float bv = bias[gc];
      if (MODE == 0) {
        ushort* C = (ushort*)Cout;
#pragma unroll
        for (int r = 0; r < 4; r++)
          C[(size_t)(gr0 + r) * H + gc] = f2b(acc[m][n][r] + bv);
      } else if (MODE == 1) {
        ushort* C = (ushort*)Cout;
        int bb = gr0 >> 11, n0 = gr0 & 2047;
        s16x4 o;
#pragma unroll
        for (int r = 0; r < 4; r++) o[r] = (short)f2b(acc[m][n][r] + bv);
        *(s16x4*)(C + (size_t)bb * (H * NCTX) + (size_t)gc * NCTX + n0) = o;
      } else {
        float* C = (float*)Cout;
#pragma unroll
        for (int r = 0; r < 4; r++)
          C[(size_t)(gr0 + r) * H + gc] = acc[m][n][r] + bv;
      }
    }
  }
}

// ---------------- flash attention (swapped QK^T, lane-local softmax) ----------------
// grid 512; XCD remap co-locates the 8 qt-siblings of each (b,h) on one XCD.
// Per wave: 16 q rows. Swapped mfma(K,Q): lane holds S[kv=nt*16+hi*4+r][q=lo].

__global__ __launch_bounds__(256) void attn_k(const ushort* __restrict__ Q,
                                              const ushort* __restrict__ K,
                                              const ushort* __restrict__ VT,
                                              const int* __restrict__ ids,
                                              const int* __restrict__ curp,
                                              ushort* __restrict__ O) {
  __shared__ ushort Ks[64 * 64];      // [kv][d], XOR-swizzled
  __shared__ ushort Vs[64 * 64];      // [d][kv], XOR-swizzled
  __shared__ ushort Ps[4][16 * 64];   // per-wave P [q][kv], XOR-swizzled
  const int blk = (blockIdx.x & 7) * 64 + (blockIdx.x >> 3);  // XCD-chunked remap (bijective on 512)
  const int qt = blk & 7;
  const int h = (blk >> 3) & 15;
  const int b = blk >> 7;
  const int cur = curp[0];
  const int tid = threadIdx.x, lane = tid & 63, w = tid >> 6;
  const int lo = lane & 15, hi = lane >> 4;
  const int swz = (lo & 7) << 4;

  const ushort* Qp = Q + ((size_t)(b * T_ + qt * 64 + w * 16 + lo)) * H + h * HD;
  bf16x8 qf0 = *(const bf16x8*)(Qp + hi * 8);        // B-frag: n=q=lo, k=hi*8+j
  bf16x8 qf1 = *(const bf16x8*)(Qp + 32 + hi * 8);

  f32x4 oacc[4];
#pragma unroll
  for (int d = 0; d < 4; d++) oacc[d] = (f32x4){0.f, 0.f, 0.f, 0.f};
  float mrow = -1e30f, lrow = 0.f;  // per-lane state for q = lo

  const int* idb = ids + b * NCTX;

  for (int kv0 = 0; kv0 < NCTX; kv0 += 64) {
    // stage 64x64 tiles, swizzled: byte = (r*128 + s*16) ^ ((r&7)<<4)
#pragma unroll
    for (int i = 0; i < 2; i++) {
      int seg = tid + i * 256;
      int r = seg >> 3, s = seg & 7;
      int wb = (r * 128 + s * 16) ^ ((r & 7) << 4);
      *(bf16x8*)((char*)Ks + wb) =
          *(const bf16x8*)(K + ((size_t)(b * NCTX + kv0 + r)) * H + h * HD + s * 8);
      *(bf16x8*)((char*)Vs + wb) =
          *(const bf16x8*)(VT + (size_t)b * (H * NCTX) + (size_t)(h * HD + r) * NCTX + kv0 + s * 8);
    }
    __syncthreads();

    // S = K Q^T (swapped): D[kv][q], lane: q=lo, kv=nt*16+hi*4+r
    f32x4 sc[4];
#pragma unroll
    for (int nt = 0; nt < 4; nt++) {
      bf16x8 kf0 = *(const bf16x8*)((char*)Ks + ((((nt * 16 + lo) * 128) + hi * 16) ^ swz));
      bf16x8 kf1 = *(const bf16x8*)((char*)Ks + ((((nt * 16 + lo) * 128) + 64 + hi * 16) ^ swz));
      f32x4 z = (f32x4){0.f, 0.f, 0.f, 0.f};
      z = __builtin_amdgcn_mfma_f32_16x16x32_bf16(kf0, qf0, z, 0, 0, 0);
      sc[nt] = __builtin_amdgcn_mfma_f32_16x16x32_bf16(kf1, qf1, z, 0, 0, 0);
    }

    // mask + scale; p[nt][r] for kv = kv0 + nt*16 + hi*4 + r
    float p[4][4];
#pragma unroll
    for (int nt = 0; nt < 4; nt++) {
      int4 iv = *(const int4*)(idb + kv0 + nt * 16 + hi * 4);
      p[nt][0] = (iv.x != cur) ? sc[nt][0] * 0.125f : -1e30f;
      p[nt][1] = (iv.y != cur) ? sc[nt][1] * 0.125f : -1e30f;
      p[nt][2] = (iv.z != cur) ? sc[nt][2] * 0.125f : -1e30f;
      p[nt][3] = (iv.w != cur) ? sc[nt][3] * 0.125f : -1e30f;
    }

    // online softmax for q=lo: in-lane 16-max + 2 shfl across hi
    float x = fmaxf(fmaxf(fmaxf(p[0][0], p[0][1]), fmaxf(p[0][2], p[0][3])),
                    fmaxf(fmaxf(p[1][0], p[1][1]), fmaxf(p[1][2], p[1][3])));
    x = fmaxf(x, fmaxf(fmaxf(fmaxf(p[2][0], p[2][1]), fmaxf(p[2][2], p[2][3])),
                       fmaxf(fmaxf(p[3][0], p[3][1]), fmaxf(p[3][2], p[3][3]))));
    x = fmaxf(x, __shfl_xor(x, 16));
    x = fmaxf(x, __shfl_xor(x, 32));
    float mn = fmaxf(mrow, x);
    float scal = __expf(mrow - mn);
    mrow = mn;
    float rs = 0.f;
#pragma unroll
    for (int nt = 0; nt < 4; nt++)
#pragma unroll
      for (int r = 0; r < 4; r++) {
        float e = __expf(p[nt][r] - mn);
        p[nt][r] = e;
        rs += e;
      }
    rs += __shfl_xor(rs, 16);
    rs += __shfl_xor(rs, 32);
    lrow = lrow * scal + rs;

    // rescale O (rows q = hi*4+r): broadcast scal from lane q
    float sq0 = __shfl(scal, hi * 4 + 0);
    float sq1 = __shfl(scal, hi * 4 + 1);
    float sq2 = __shfl(scal, hi * 4 + 2);
    float sq3 = __shfl(scal, hi * 4 + 3);
#pragma unroll
    for (int d = 0; d < 4; d++) {
      oacc[d][0] *= sq0; oacc[d][1] *= sq1; oacc[d][2] *= sq2; oacc[d][3] *= sq3;
    }

    // P -> per-wave LDS row q=lo (vector b64 writes, no barrier needed)
#pragma unroll
    for (int nt = 0; nt < 4; nt++) {
      s16x4 pw;
#pragma unroll
      for (int r = 0; r < 4; r++) pw[r] = (short)f2b(p[nt][r]);
      *(s16x4*)((char*)Ps[w] + ((lo * 128 + (nt * 16 + hi * 4) * 2) ^ swz)) = pw;
    }

    // PV: oacc[d] += P[q][kv] @ V^T[d][kv]
#pragma unroll
    for (int ks = 0; ks < 2; ks++) {
      bf16x8 pa = *(const bf16x8*)((char*)Ps[w] + ((lo * 128 + (ks * 64 + hi * 16)) ^ swz));
#pragma unroll
      for (int d = 0; d < 4; d++) {
        bf16x8 vf = *(const bf16x8*)((char*)Vs + (((d * 16 + lo) * 128 + ks * 64 + hi * 16) ^ swz));
        oacc[d] = __builtin_amdgcn_mfma_f32_16x16x32_bf16(pa, vf, oacc[d], 0, 0, 0);
      }
    }
    __syncthreads();
  }

  // normalize + store: oacc rows q=hi*4+r, cols d*16+lo
  float lr0 = __shfl(lrow, hi * 4 + 0);
  float lr1 = __shfl(lrow, hi * 4 + 1);
  float lr2 = __shfl(lrow, hi * 4 + 2);
  float lr3 = __shfl(lrow, hi * 4 + 3);
#pragma unroll
  for (int d = 0; d < 4; d++) {
    int t = qt * 64 + w * 16 + hi * 4;
    size_t base = ((size_t)(b * T_ + t)) * H + h * HD + d * 16 + lo;
    O[base] = f2b(oacc[d][0] / lr0);
    O[base + H] = f2b(oacc[d][1] / lr1);
    O[base + 2 * H] = f2b(oacc[d][2] / lr2);
    O[base + 3 * H] = f2b(oacc[d][3] / lr3);
  }
}

// ---------------- launch ----------------

extern "C" void kernel_launch(void* const* d_in, const int* in_sizes, int n_in,
                              void* d_out, int out_size, void* d_ws, size_t ws_size,
                              hipStream_t stream) {
  const float* query = (const float*)d_in[0];
  const float* context = (const float*)d_in[1];
  const int* ids = (const int*)d_in[2];
  const int* curp = (const int*)d_in[3];
  const int* bars = (const int*)d_in[4];
  const float* Wq = (const float*)d_in[5];
  const float* bq = (const float*)d_in[6];
  const float* Wk = (const float*)d_in[7];
  const float* bk = (const float*)d_in[8];
  const float* Wv = (const float*)d_in[9];
  const float* bv = (const float*)d_in[10];
  const float* Wo = (const float*)d_in[11];
  const float* bo = (const float*)d_in[12];
  const float* iemb = (const float*)d_in[13];
  const float* bemb = (const float*)d_in[14];
  float* out = (float*)d_out;

  ushort* ws = (ushort*)d_ws;
  ushort* Wqb = ws;
  ushort* Wkb = Wqb + (1u << 20);
  ushort* Wvb = Wkb + (1u << 20);
  ushort* Wob = Wvb + (1u << 20);
  ushort* qin = Wob + (1u << 20);
  ushort* ctxb = qin + (2u << 20);
  ushort* Qb = ctxb + (8u << 20);
  ushort* Kb = Qb + (2u << 20);
  ushort* VTb = Kb + (8u << 20);
  ushort* AOb = VTb + (8u << 20);

  cvt_kernel<<<1024, 256, 0, stream>>>(Wq, Wqb);
  cvt_kernel<<<1024, 256, 0, stream>>>(Wk, Wkb);
  cvt_kernel<<<1024, 256, 0, stream>>>(Wv, Wvb);
  cvt_kernel<<<1024, 256, 0, stream>>>(Wo, Wob);
  prep_q_kernel<<<2048, 256, 0, stream>>>(query, iemb, curp, qin);
  prep_ctx_kernel<<<8192, 256, 0, stream>>>(context, iemb, bemb, ids, bars, ctxb);

  gemm_k<0><<<dim3(8, 16), 256, 0, stream>>>(qin, Wqb, bq, Qb);    // Q
  gemm_k<0><<<dim3(8, 64), 256, 0, stream>>>(ctxb, Wkb, bk, Kb);   // K
  gemm_k<1><<<dim3(8, 64), 256, 0, stream>>>(ctxb, Wvb, bv, VTb);  // V (transposed)

  attn_k<<<512, 256, 0, stream>>>(Qb, Kb, VTb, ids, curp, AOb);

  gemm_k<2><<<dim3(8, 16), 256, 0, stream>>>(AOb, Wob, bo, out);   // out proj
}